// Round 2
// baseline (244.791 us; speedup 1.0000x reference)
//
#include <hip/hip_runtime.h>

using int32x4 = __attribute__((ext_vector_type(4))) int;

#define BM 128
#define BN 128
#define BK 64   // K bytes per step (one mfma_i32_16x16x64_i8 per fragment)

// ---------------------------------------------------------------------------
// Kernel 1: pack int32 activations -> int8 (values guaranteed in [-128,127])
// Each thread: 4x dwordx4 loads (16 int32) -> 1x dwordx4 store (16 int8)
// ---------------------------------------------------------------------------
__global__ __launch_bounds__(256) void pack_x_kernel(const int32x4* __restrict__ x,
                                                     int32x4* __restrict__ xp,
                                                     int nvec /* total elems / 16 */) {
    int t = blockIdx.x * 256 + threadIdx.x;
    if (t >= nvec) return;
    int32x4 a = x[t * 4 + 0];
    int32x4 b = x[t * 4 + 1];
    int32x4 c = x[t * 4 + 2];
    int32x4 d = x[t * 4 + 3];
    int32x4 o;
    o.x = (a.x & 255) | ((a.y & 255) << 8) | ((a.z & 255) << 16) | (a.w << 24);
    o.y = (b.x & 255) | ((b.y & 255) << 8) | ((b.z & 255) << 16) | (b.w << 24);
    o.z = (c.x & 255) | ((c.y & 255) << 8) | ((c.z & 255) << 16) | (c.w << 24);
    o.w = (d.x & 255) | ((d.y & 255) << 8) | ((d.z & 255) << 16) | (d.w << 24);
    xp[t] = o;
}

// ---------------------------------------------------------------------------
// Kernel 2: weight transform — int32 [K][N] -> int8 [N][K] (pack + transpose)
// 64x64 tiles via LDS, 256 threads/block.
// ---------------------------------------------------------------------------
__global__ __launch_bounds__(256) void transform_w_kernel(const int* __restrict__ w,
                                                          unsigned char* __restrict__ wt,
                                                          int K, int N) {
    __shared__ unsigned char tileT[64][72];  // [n_local][k_local], padded stride
    int tx = threadIdx.x & 15;
    int ty = threadIdx.x >> 4;
    int n0 = blockIdx.x * 64;
    int k0 = blockIdx.y * 64;
#pragma unroll
    for (int r = 0; r < 4; ++r) {
        int row = ty * 4 + r;  // k_local
        int32x4 v = *(const int32x4*)&w[(size_t)(k0 + row) * N + n0 + tx * 4];
        tileT[tx * 4 + 0][row] = (unsigned char)(v.x & 255);
        tileT[tx * 4 + 1][row] = (unsigned char)(v.y & 255);
        tileT[tx * 4 + 2][row] = (unsigned char)(v.z & 255);
        tileT[tx * 4 + 3][row] = (unsigned char)(v.w & 255);
    }
    __syncthreads();
#pragma unroll
    for (int r = 0; r < 4; ++r) {
        int row = ty * 4 + r;  // n_local
        uchar4 v = *(const uchar4*)&tileT[row][tx * 4];
        *(uchar4*)&wt[(size_t)(n0 + row) * K + k0 + tx * 4] = v;
    }
}

// ---------------------------------------------------------------------------
// Kernel 3: int8 GEMM  C[M][N] = Xp[M][K] * Wt[N][K]^T  (+bias, >>shift)
// m97 structure: 128x128 tile, BK=64, 4 waves 2x2, global_load_lds staging.
// ---------------------------------------------------------------------------
__global__ __launch_bounds__(256) void gemm_i8_kernel(const char* __restrict__ A,   // [M][K]
                                                      const char* __restrict__ Bt,  // [N][K]
                                                      const int* __restrict__ bias, // [N]
                                                      const int* __restrict__ shiftp,
                                                      int* __restrict__ C,          // [M][N]
                                                      int M, int N, int K) {
    __shared__ char As[BM * BK];  // 8 KiB
    __shared__ char Bs[BN * BK];  // 8 KiB

    int nbn = N / BN;
    int nwg = gridDim.x;
    int bid = blockIdx.x;
    // XCD-aware swizzle (nwg is a multiple of 8 here -> bijective)
    int cpx = nwg >> 3;
    int swz = (bid & 7) * cpx + (bid >> 3);
    int bm = swz / nbn;
    int bn = swz % nbn;
    int m0 = bm * BM;
    int n0 = bn * BN;

    int tid = threadIdx.x;
    int lane = tid & 63;
    int wave = tid >> 6;
    int wr = wave >> 1;  // wave row in 2x2
    int wc = wave & 1;   // wave col

    int32x4 acc[4][4] = {};

    // staging geometry: chunk p = tid*16 + i*4096 ; row = p>>6, col = p&63
    int p0 = tid * 16;
    int row0 = p0 >> 6, col0 = p0 & 63;
    int p1 = p0 + 4096;
    int row1 = p1 >> 6, col1 = p1 & 63;

    const size_t ldk = (size_t)K;

    int lrow = lane & 15;
    int lk = (lane >> 4) * 16;

    for (int kt = 0; kt < K; kt += BK) {
        // ---- stage A and B tiles (direct global->LDS, 16B per lane) ----
        __builtin_amdgcn_global_load_lds(
            (const __attribute__((address_space(1))) void*)(A + (size_t)(m0 + row0) * ldk + kt + col0),
            (__attribute__((address_space(3))) void*)(As + p0), 16, 0, 0);
        __builtin_amdgcn_global_load_lds(
            (const __attribute__((address_space(1))) void*)(A + (size_t)(m0 + row1) * ldk + kt + col1),
            (__attribute__((address_space(3))) void*)(As + p1), 16, 0, 0);
        __builtin_amdgcn_global_load_lds(
            (const __attribute__((address_space(1))) void*)(Bt + (size_t)(n0 + row0) * ldk + kt + col0),
            (__attribute__((address_space(3))) void*)(Bs + p0), 16, 0, 0);
        __builtin_amdgcn_global_load_lds(
            (const __attribute__((address_space(1))) void*)(Bt + (size_t)(n0 + row1) * ldk + kt + col1),
            (__attribute__((address_space(3))) void*)(Bs + p1), 16, 0, 0);
        __syncthreads();  // drains vmcnt before barrier

        // ---- fragments ----
        int32x4 af[4], bf[4];
#pragma unroll
        for (int m = 0; m < 4; ++m)
            af[m] = *(const int32x4*)&As[(wr * 64 + m * 16 + lrow) * BK + lk];
#pragma unroll
        for (int n = 0; n < 4; ++n)
            bf[n] = *(const int32x4*)&Bs[(wc * 64 + n * 16 + lrow) * BK + lk];

#pragma unroll
        for (int m = 0; m < 4; ++m)
#pragma unroll
            for (int n = 0; n < 4; ++n)
                acc[m][n] = __builtin_amdgcn_mfma_i32_16x16x64_i8(af[m], bf[n], acc[m][n], 0, 0, 0);

        __syncthreads();
    }

    // ---- epilogue: bias + arithmetic shift, int32 store ----
    int s = *shiftp;
    int crow = (lane >> 4) * 4;
    int ccol = lane & 15;
#pragma unroll
    for (int n = 0; n < 4; ++n) {
        int gcol = n0 + wc * 64 + n * 16 + ccol;
        int bv = bias[gcol];
#pragma unroll
        for (int m = 0; m < 4; ++m) {
            int grow0 = m0 + wr * 64 + m * 16 + crow;
#pragma unroll
            for (int r = 0; r < 4; ++r) {
                int y = acc[m][n][r] + bv;
                y = (s > 0) ? (y >> s) : y;
                C[(size_t)(grow0 + r) * N + gcol] = y;
            }
        }
    }
}

// ---------------------------------------------------------------------------
extern "C" void kernel_launch(void* const* d_in, const int* in_sizes, int n_in,
                              void* d_out, int out_size, void* d_ws, size_t ws_size,
                              hipStream_t stream) {
    const int* x = (const int*)d_in[0];
    const int* w = (const int*)d_in[1];   // int8 values stored as int32 (harness contract)
    const int* bias = (const int*)d_in[2];
    const int* shiftp = (const int*)d_in[3];
    int* out = (int*)d_out;

    const int N = in_sizes[2];           // d_out feature dim (4096)
    const int K = in_sizes[1] / N;       // d_in feature dim  (4096)
    const int M = in_sizes[0] / K;       // tokens            (8192)

    // workspace layout: [0, M*K) packed int8 X ; [M*K, M*K + K*N) transposed int8 W
    char* xp = (char*)d_ws;
    unsigned char* wt = (unsigned char*)d_ws + (size_t)M * K;

    // 1) pack x int32 -> int8
    int nvec = (int)(((long long)M * K) / 16);
    pack_x_kernel<<<(nvec + 255) / 256, 256, 0, stream>>>((const int32x4*)x, (int32x4*)xp, nvec);

    // 2) transform W: int32 [K][N] -> int8 [N][K]
    dim3 tgrid(N / 64, K / 64);
    transform_w_kernel<<<tgrid, 256, 0, stream>>>(w, wt, K, N);

    // 3) GEMM + bias + shift
    int nwg = (M / BM) * (N / BN);
    gemm_i8_kernel<<<nwg, 256, 0, stream>>>(xp, (const char*)wt, bias, shiftp, out, M, N, K);
}

// Round 3
// 193.537 us; speedup vs baseline: 1.2648x; 1.2648x over previous
//
#include <hip/hip_runtime.h>

using int32x4 = __attribute__((ext_vector_type(4))) int;

#define BM 256
#define BN 256
#define BKB 128        // K bytes per K-tile (2 MFMA k-slices of 64)
#define HT 16384       // half-tile bytes (256 rows x 64 B)
#define BUF 65536      // one K-tile buffer: [Ak0][Bk0][Ak1][Bk1]

// ---------------------------------------------------------------------------
// Kernel 1: pack int32 activations -> int8 (values in [-128,127])
// ---------------------------------------------------------------------------
__global__ __launch_bounds__(256) void pack_x_kernel(const int32x4* __restrict__ x,
                                                     int32x4* __restrict__ xp,
                                                     int nvec) {
    int t = blockIdx.x * 256 + threadIdx.x;
    if (t >= nvec) return;
    int32x4 a = x[t * 4 + 0];
    int32x4 b = x[t * 4 + 1];
    int32x4 c = x[t * 4 + 2];
    int32x4 d = x[t * 4 + 3];
    int32x4 o;
    o.x = (a.x & 255) | ((a.y & 255) << 8) | ((a.z & 255) << 16) | (a.w << 24);
    o.y = (b.x & 255) | ((b.y & 255) << 8) | ((b.z & 255) << 16) | (b.w << 24);
    o.z = (c.x & 255) | ((c.y & 255) << 8) | ((c.z & 255) << 16) | (c.w << 24);
    o.w = (d.x & 255) | ((d.y & 255) << 8) | ((d.z & 255) << 16) | (d.w << 24);
    xp[t] = o;
}

// ---------------------------------------------------------------------------
// Kernel 2: weight transform — int32 [K][N] -> int8 [N][K]
// ---------------------------------------------------------------------------
__global__ __launch_bounds__(256) void transform_w_kernel(const int* __restrict__ w,
                                                          unsigned char* __restrict__ wt,
                                                          int K, int N) {
    __shared__ unsigned char tileT[64][72];
    int tx = threadIdx.x & 15;
    int ty = threadIdx.x >> 4;
    int n0 = blockIdx.x * 64;
    int k0 = blockIdx.y * 64;
#pragma unroll
    for (int r = 0; r < 4; ++r) {
        int row = ty * 4 + r;  // k_local
        int32x4 v = *(const int32x4*)&w[(size_t)(k0 + row) * N + n0 + tx * 4];
        tileT[tx * 4 + 0][row] = (unsigned char)(v.x & 255);
        tileT[tx * 4 + 1][row] = (unsigned char)(v.y & 255);
        tileT[tx * 4 + 2][row] = (unsigned char)(v.z & 255);
        tileT[tx * 4 + 3][row] = (unsigned char)(v.w & 255);
    }
    __syncthreads();
#pragma unroll
    for (int r = 0; r < 4; ++r) {
        int row = ty * 4 + r;  // n_local
        uchar4 v = *(const uchar4*)&tileT[row][tx * 4];
        *(uchar4*)&wt[(size_t)(n0 + row) * K + k0 + tx * 4] = v;
    }
}

// ---------------------------------------------------------------------------
// Kernel 3: int8 GEMM, 256x256 tile, 4-phase counted-vmcnt pipeline (T2-T5)
// ---------------------------------------------------------------------------
__global__ __launch_bounds__(512, 2) void gemm_i8_8ph(
    const char* __restrict__ A,   // [M][K] int8
    const char* __restrict__ Bt,  // [N][K] int8
    const int* __restrict__ bias,
    const int* __restrict__ shiftp,
    int* __restrict__ C,          // [M][N]
    int M, int N, int K) {
    __shared__ char smem[2 * BUF];  // 128 KiB: 2 x [Ak0|Bk0|Ak1|Bk1]

    const int nbn = N / BN;
    const int nwg = gridDim.x;
    const int bid = blockIdx.x;
    const int cpx = nwg >> 3;  // nwg % 8 == 0 -> bijective XCD swizzle
    const int swz = (bid & 7) * cpx + (bid >> 3);
    const int m0 = (swz / nbn) * BM;
    const int n0 = (swz % nbn) * BN;

    const int t = threadIdx.x;
    const int lane = t & 63;
    const int wave = t >> 6;
    const int wr = wave >> 2;  // 0..1  (M half)
    const int wc = wave & 3;   // 0..3  (N quarter)

    // ---- staging geometry (global source pre-swizzled, LDS dest linear) ----
    // LDS linear byte o = j*8192 + t*16 -> row = j*128 + (t>>2), col = (t&3)*16
    // source col = col ^ xor(row), xor(row) = ((row>>1)&3)<<4 = ((t>>3)&3)<<4
    const int s_row = t >> 2;
    const int s_col = ((t & 3) << 4) ^ (((t >> 3) & 3) << 4);
    const char* a_src = A + (size_t)(m0 + s_row) * K + s_col;
    const char* b_src = Bt + (size_t)(n0 + s_row) * K + s_col;
    const size_t jstr = (size_t)128 * K;
    char* lds_st = smem + t * 16;

    // ---- fragment-read geometry (swizzled read) ----
    const int lr = lane & 15;
    const int lc = (lane >> 4) << 4;
    const int xr = ((lr >> 1) & 3) << 4;  // row bits 1-2 == lr bits 1-2 (mf*16 = 0 mod 4 after >>1)
    const int a_off = ((wr << 7) + lr) * 64 + (lc ^ xr);       // + mf*1024 + ks*32768
    const int b_off = HT + ((wc << 6) + lr) * 64 + (lc ^ xr);  // + nf*1024 + ks*32768

    int32x4 acc[8][4] = {};

    const int nt = K / BKB;  // 32

#define GLL(src, dst)                                                 \
    __builtin_amdgcn_global_load_lds(                                 \
        (const __attribute__((address_space(1))) void*)(src),        \
        (__attribute__((address_space(3))) void*)(dst), 16, 0, 0)

#define STAGE(mat, kcol, h, b)                                   \
    do {                                                         \
        GLL((mat) + (kcol), lds_st + (b)*BUF + (h)*HT);          \
        GLL((mat) + jstr + (kcol), lds_st + (b)*BUF + (h)*HT + 8192); \
    } while (0)

#define FENCE asm volatile("" ::: "memory")
#define BARR                           \
    do {                               \
        FENCE;                         \
        __builtin_amdgcn_s_barrier();  \
        FENCE;                         \
    } while (0)
#define LGKM0                                                   \
    do {                                                        \
        asm volatile("s_waitcnt lgkmcnt(0)" ::: "memory");      \
        __builtin_amdgcn_sched_barrier(0);                      \
    } while (0)
#define VMW(n)                                                  \
    do {                                                        \
        asm volatile("s_waitcnt vmcnt(" #n ")" ::: "memory");   \
        __builtin_amdgcn_sched_barrier(0);                      \
    } while (0)

    // ---- prologue: stage K-tile 0 into buf 0 (h0=Ak0,h1=Bk0,h2=Ak1,h3=Bk1) ----
    STAGE(a_src, 0, 0, 0);
    STAGE(b_src, 0, 1, 0);
    STAGE(a_src, 64, 2, 0);
    STAGE(b_src, 64, 3, 0);
    VMW(4);  // wait h0,h1 (oldest 4 loads); h2,h3 stay in flight
    BARR;

    for (int tt = 0; tt < nt; ++tt) {
        const int cur = tt & 1;
        const int nxt = cur ^ 1;
        const size_t kc = (size_t)(tt + 1) * BKB;
        const bool st = (tt + 1) < nt;
        const int ab = cur * BUF + a_off;
        const int bb = cur * BUF + b_off;
        int32x4 af[4], bf[4];

        // ===== phase 1: k-slice 0, m-frags 0-3 (8 ds_read) =====
#pragma unroll
        for (int i = 0; i < 4; ++i) af[i] = *(const int32x4*)&smem[ab + i * 1024];
#pragma unroll
        for (int i = 0; i < 4; ++i) bf[i] = *(const int32x4*)&smem[bb + i * 1024];
        if (st) STAGE(a_src, kc, 0, nxt);  // next tile Ak0
        BARR;
        LGKM0;
        __builtin_amdgcn_s_setprio(1);
#pragma unroll
        for (int i = 0; i < 4; ++i)
#pragma unroll
            for (int j = 0; j < 4; ++j)
                acc[i][j] = __builtin_amdgcn_mfma_i32_16x16x64_i8(af[i], bf[j], acc[i][j], 0, 0, 0);
        __builtin_amdgcn_s_setprio(0);
        BARR;

        // ===== phase 2: k-slice 0, m-frags 4-7 (4 ds_read, reuse bf) =====
#pragma unroll
        for (int i = 0; i < 4; ++i) af[i] = *(const int32x4*)&smem[ab + (4 + i) * 1024];
        if (st) STAGE(b_src, kc, 1, nxt);  // next tile Bk0
        BARR;
        LGKM0;
        __builtin_amdgcn_s_setprio(1);
#pragma unroll
        for (int i = 0; i < 4; ++i)
#pragma unroll
            for (int j = 0; j < 4; ++j)
                acc[4 + i][j] = __builtin_amdgcn_mfma_i32_16x16x64_i8(af[i], bf[j], acc[4 + i][j], 0, 0, 0);
        __builtin_amdgcn_s_setprio(0);
        // publish own h2,h3 (oldest 4 of <=8 outstanding); keep next h0,h1 in flight
        if (st) { VMW(4); } else { VMW(0); }
        BARR;

        // ===== phase 3: k-slice 1, m-frags 0-3 (8 ds_read) =====
#pragma unroll
        for (int i = 0; i < 4; ++i) af[i] = *(const int32x4*)&smem[ab + 32768 + i * 1024];
#pragma unroll
        for (int i = 0; i < 4; ++i) bf[i] = *(const int32x4*)&smem[bb + 32768 + i * 1024];
        if (st) STAGE(a_src, kc + 64, 2, nxt);  // next tile Ak1
        BARR;
        LGKM0;
        __builtin_amdgcn_s_setprio(1);
#pragma unroll
        for (int i = 0; i < 4; ++i)
#pragma unroll
            for (int j = 0; j < 4; ++j)
                acc[i][j] = __builtin_amdgcn_mfma_i32_16x16x64_i8(af[i], bf[j], acc[i][j], 0, 0, 0);
        __builtin_amdgcn_s_setprio(0);
        BARR;

        // ===== phase 4: k-slice 1, m-frags 4-7 (4 ds_read, reuse bf) =====
#pragma unroll
        for (int i = 0; i < 4; ++i) af[i] = *(const int32x4*)&smem[ab + 32768 + (4 + i) * 1024];
        if (st) STAGE(b_src, kc + 64, 3, nxt);  // next tile Bk1
        BARR;
        LGKM0;
        __builtin_amdgcn_s_setprio(1);
#pragma unroll
        for (int i = 0; i < 4; ++i)
#pragma unroll
            for (int j = 0; j < 4; ++j)
                acc[4 + i][j] = __builtin_amdgcn_mfma_i32_16x16x64_i8(af[i], bf[j], acc[4 + i][j], 0, 0, 0);
        __builtin_amdgcn_s_setprio(0);
        // publish next tile's h0,h1 (oldest 4; its h2,h3 stay in flight)
        if (st) VMW(4);
        BARR;
    }

    // ---- epilogue: bias + shift, int32 store ----
    const int s = *shiftp;
    const int crow = (lane >> 4) << 2;
    const int ccol = lane & 15;
    int bv[4];
#pragma unroll
    for (int nf = 0; nf < 4; ++nf) bv[nf] = bias[n0 + wc * 64 + nf * 16 + ccol];
#pragma unroll
    for (int mf = 0; mf < 8; ++mf) {
        const int grow0 = m0 + wr * 128 + mf * 16 + crow;
#pragma unroll
        for (int nf = 0; nf < 4; ++nf) {
            const int gcol = n0 + wc * 64 + nf * 16 + ccol;
#pragma unroll
            for (int r = 0; r < 4; ++r) {
                int y = acc[mf][nf][r] + bv[nf];
                y = (s > 0) ? (y >> s) : y;
                C[(size_t)(grow0 + r) * N + gcol] = y;
            }
        }
    }
#undef GLL
#undef STAGE
#undef FENCE
#undef BARR
#undef LGKM0
#undef VMW
}

// ---------------------------------------------------------------------------
extern "C" void kernel_launch(void* const* d_in, const int* in_sizes, int n_in,
                              void* d_out, int out_size, void* d_ws, size_t ws_size,
                              hipStream_t stream) {
    const int* x = (const int*)d_in[0];
    const int* w = (const int*)d_in[1];   // int8 values stored as int32
    const int* bias = (const int*)d_in[2];
    const int* shiftp = (const int*)d_in[3];
    int* out = (int*)d_out;

    const int N = in_sizes[2];      // 4096
    const int K = in_sizes[1] / N;  // 4096
    const int M = in_sizes[0] / K;  // 8192

    char* xp = (char*)d_ws;
    unsigned char* wt = (unsigned char*)d_ws + (size_t)M * K;

    int nvec = (int)(((long long)M * K) / 16);
    pack_x_kernel<<<(nvec + 255) / 256, 256, 0, stream>>>((const int32x4*)x, (int32x4*)xp, nvec);

    dim3 tgrid(N / 64, K / 64);
    transform_w_kernel<<<tgrid, 256, 0, stream>>>(w, wt, K, N);

    int nwg = (M / BM) * (N / BN);  // 512, %8==0
    gemm_i8_8ph<<<nwg, 512, 0, stream>>>(xp, (const char*)wt, bias, shiftp, out, M, N, K);
}

// Round 4
// 188.765 us; speedup vs baseline: 1.2968x; 1.0253x over previous
//
#include <hip/hip_runtime.h>

using int32x4 = __attribute__((ext_vector_type(4))) int;

#define BM 256
#define BN 256
#define TBUF 32768   // one K-tile buffer: A(16K) + B(16K); K-tile = 64 bytes of K

// ---------------------------------------------------------------------------
// Kernel 1: pack int32 activations -> int8 (values in [-128,127])
// ---------------------------------------------------------------------------
__global__ __launch_bounds__(256) void pack_x_kernel(const int32x4* __restrict__ x,
                                                     int32x4* __restrict__ xp,
                                                     int nvec) {
    int t = blockIdx.x * 256 + threadIdx.x;
    if (t >= nvec) return;
    int32x4 a = x[t * 4 + 0];
    int32x4 b = x[t * 4 + 1];
    int32x4 c = x[t * 4 + 2];
    int32x4 d = x[t * 4 + 3];
    int32x4 o;
    o.x = (a.x & 255) | ((a.y & 255) << 8) | ((a.z & 255) << 16) | (a.w << 24);
    o.y = (b.x & 255) | ((b.y & 255) << 8) | ((b.z & 255) << 16) | (b.w << 24);
    o.z = (c.x & 255) | ((c.y & 255) << 8) | ((c.z & 255) << 16) | (c.w << 24);
    o.w = (d.x & 255) | ((d.y & 255) << 8) | ((d.z & 255) << 16) | (d.w << 24);
    xp[t] = o;
}

// ---------------------------------------------------------------------------
// Kernel 2: weight transform — int32 [K][N] -> int8 [N][K]
// ---------------------------------------------------------------------------
__global__ __launch_bounds__(256) void transform_w_kernel(const int* __restrict__ w,
                                                          unsigned char* __restrict__ wt,
                                                          int K, int N) {
    __shared__ unsigned char tileT[64][72];
    int tx = threadIdx.x & 15;
    int ty = threadIdx.x >> 4;
    int n0 = blockIdx.x * 64;
    int k0 = blockIdx.y * 64;
#pragma unroll
    for (int r = 0; r < 4; ++r) {
        int row = ty * 4 + r;  // k_local
        int32x4 v = *(const int32x4*)&w[(size_t)(k0 + row) * N + n0 + tx * 4];
        tileT[tx * 4 + 0][row] = (unsigned char)(v.x & 255);
        tileT[tx * 4 + 1][row] = (unsigned char)(v.y & 255);
        tileT[tx * 4 + 2][row] = (unsigned char)(v.z & 255);
        tileT[tx * 4 + 3][row] = (unsigned char)(v.w & 255);
    }
    __syncthreads();
#pragma unroll
    for (int r = 0; r < 4; ++r) {
        int row = ty * 4 + r;  // n_local
        uchar4 v = *(const uchar4*)&tileT[row][tx * 4];
        *(uchar4*)&wt[(size_t)(n0 + row) * K + k0 + tx * 4] = v;
    }
}

// ---------------------------------------------------------------------------
// Kernel 3: int8 GEMM, 256x256 tile, 4-deep circular buffer, counted vmcnt.
// Per K-tile (64 B of K): 2 phases x 16 MFMA. Stage tile t+3 during tile t.
// ---------------------------------------------------------------------------
__global__ __launch_bounds__(512, 2) void gemm_i8_deep(
    const char* __restrict__ A,   // [M][K] int8
    const char* __restrict__ Bt,  // [N][K] int8
    const int* __restrict__ bias,
    const int* __restrict__ shiftp,
    int* __restrict__ C,          // [M][N]
    int M, int N, int K) {
    __shared__ char smem[4 * TBUF];  // 128 KiB

    const int nbn = N / BN;
    const int nwg = gridDim.x;
    const int bid = blockIdx.x;
    const int cpx = nwg >> 3;  // nwg % 8 == 0 -> bijective XCD swizzle
    const int swz = (bid & 7) * cpx + (bid >> 3);
    const int m0 = (swz / nbn) * BM;
    const int n0 = (swz % nbn) * BN;

    const int t = threadIdx.x;
    const int lane = t & 63;
    const int wave = t >> 6;
    const int wr = wave >> 2;  // 0..1  (M half)
    const int wc = wave & 3;   // 0..3  (N quarter)

    // ---- staging geometry (pre-swizzled global source, linear LDS dest) ----
    // LDS linear byte o = j*8192 + t*16 -> row = j*128 + (t>>2), col = (t&3)*16
    // xor(row) = ((row>>1)&3)<<4 = ((t>>3)&3)<<4
    const int s_row = t >> 2;
    const int s_col = ((t & 3) << 4) ^ (((t >> 3) & 3) << 4);
    const char* a_src = A + (size_t)(m0 + s_row) * K + s_col;
    const char* b_src = Bt + (size_t)(n0 + s_row) * K + s_col;
    const size_t jstr = (size_t)128 * K;
    char* lds_st = smem + t * 16;

    // ---- fragment-read geometry (swizzled read) ----
    const int lr = lane & 15;
    const int lc = (lane >> 4) << 4;
    const int xr = ((lr >> 1) & 3) << 4;
    const int a_off = ((wr << 7) + lr) * 64 + (lc ^ xr);          // + mf*1024
    const int b_off = 16384 + ((wc << 6) + lr) * 64 + (lc ^ xr);  // + nf*1024

    int32x4 acc[8][4] = {};

    const int nt = K / 64;  // 64 K-tiles

#define GLL(src, dst)                                                 \
    __builtin_amdgcn_global_load_lds(                                 \
        (const __attribute__((address_space(1))) void*)(src),        \
        (__attribute__((address_space(3))) void*)(dst), 16, 0, 0)

#define FENCE asm volatile("" ::: "memory")
#define BARR                           \
    do {                               \
        FENCE;                         \
        __builtin_amdgcn_s_barrier();  \
        FENCE;                         \
    } while (0)
#define LGKM0                                                   \
    do {                                                        \
        asm volatile("s_waitcnt lgkmcnt(0)" ::: "memory");      \
        __builtin_amdgcn_sched_barrier(0);                      \
    } while (0)
#define VMW(n)                                                  \
    do {                                                        \
        asm volatile("s_waitcnt vmcnt(" #n ")" ::: "memory");   \
        __builtin_amdgcn_sched_barrier(0);                      \
    } while (0)

    // One K-tile: 2 phases. Stage tile TT+3 (A in ph1, B in ph2) into buf (TT+3)&3.
#define TILE(TT, DOSTAGE, VMWSTMT)                                                     \
    do {                                                                               \
        const int base_ = ((TT) & 3) * TBUF;                                           \
        const int sb_ = (((TT) + 3) & 3) * TBUF;                                       \
        const size_t kc_ = (size_t)((TT) + 3) * 64;                                    \
        int32x4 af[4], bf[4];                                                          \
        _Pragma("unroll") for (int i = 0; i < 4; ++i)                                  \
            af[i] = *(const int32x4*)&smem[base_ + a_off + i * 1024];                  \
        _Pragma("unroll") for (int i = 0; i < 4; ++i)                                  \
            bf[i] = *(const int32x4*)&smem[base_ + b_off + i * 1024];                  \
        if (DOSTAGE) {                                                                 \
            GLL(a_src + kc_, lds_st + sb_);                                            \
            GLL(a_src + jstr + kc_, lds_st + sb_ + 8192);                              \
        }                                                                              \
        BARR;                                                                          \
        LGKM0;                                                                         \
        __builtin_amdgcn_s_setprio(1);                                                 \
        _Pragma("unroll") for (int i = 0; i < 4; ++i)                                  \
            _Pragma("unroll") for (int j = 0; j < 4; ++j)                              \
                acc[i][j] =                                                            \
                    __builtin_amdgcn_mfma_i32_16x16x64_i8(af[i], bf[j], acc[i][j], 0, 0, 0); \
        __builtin_amdgcn_s_setprio(0);                                                 \
        BARR;                                                                          \
        _Pragma("unroll") for (int i = 0; i < 4; ++i)                                  \
            af[i] = *(const int32x4*)&smem[base_ + a_off + (4 + i) * 1024];            \
        if (DOSTAGE) {                                                                 \
            GLL(b_src + kc_, lds_st + sb_ + 16384);                                    \
            GLL(b_src + jstr + kc_, lds_st + sb_ + 16384 + 8192);                      \
        }                                                                              \
        BARR;                                                                          \
        LGKM0;                                                                         \
        __builtin_amdgcn_s_setprio(1);                                                 \
        _Pragma("unroll") for (int i = 0; i < 4; ++i)                                  \
            _Pragma("unroll") for (int j = 0; j < 4; ++j)                              \
                acc[4 + i][j] =                                                        \
                    __builtin_amdgcn_mfma_i32_16x16x64_i8(af[i], bf[j], acc[4 + i][j], 0, 0, 0); \
        __builtin_amdgcn_s_setprio(0);                                                 \
        VMWSTMT;                                                                       \
        BARR;                                                                          \
    } while (0)

    // ---- prologue: stage tiles 0,1,2 into bufs 0,1,2 (12 loads, tile order) ----
#pragma unroll
    for (int p = 0; p < 3; ++p) {
        GLL(a_src + p * 64, lds_st + p * TBUF);
        GLL(a_src + jstr + p * 64, lds_st + p * TBUF + 8192);
        GLL(b_src + p * 64, lds_st + p * TBUF + 16384);
        GLL(b_src + jstr + p * 64, lds_st + p * TBUF + 24576);
    }
    VMW(8);  // tile 0's 4 loads done; tiles 1,2 in flight
    BARR;

    // ---- main loop: VMW(8) at tile end drains exactly tile t+1's loads ----
    int tt = 0;
    for (; tt < nt - 3; ++tt) TILE(tt, 1, VMW(8));
    TILE(tt, 0, VMW(4)); ++tt;  // t = nt-3: only tile nt-1's 4 loads remain in flight
    TILE(tt, 0, VMW(0)); ++tt;  // t = nt-2: drain everything
    TILE(tt, 0, (void)0);       // t = nt-1

    // ---- epilogue: bias + shift, int32 store ----
    const int s = *shiftp;
    const int crow = (lane >> 4) << 2;
    const int ccol = lane & 15;
    int bv[4];
#pragma unroll
    for (int nf = 0; nf < 4; ++nf) bv[nf] = bias[n0 + wc * 64 + nf * 16 + ccol];
#pragma unroll
    for (int mf = 0; mf < 8; ++mf) {
        const int grow0 = m0 + wr * 128 + mf * 16 + crow;
#pragma unroll
        for (int nf = 0; nf < 4; ++nf) {
            const int gcol = n0 + wc * 64 + nf * 16 + ccol;
#pragma unroll
            for (int r = 0; r < 4; ++r) {
                int y = acc[mf][nf][r] + bv[nf];
                y = (s > 0) ? (y >> s) : y;
                C[(size_t)(grow0 + r) * N + gcol] = y;
            }
        }
    }
#undef GLL
#undef FENCE
#undef BARR
#undef LGKM0
#undef VMW
#undef TILE
}

// ---------------------------------------------------------------------------
extern "C" void kernel_launch(void* const* d_in, const int* in_sizes, int n_in,
                              void* d_out, int out_size, void* d_ws, size_t ws_size,
                              hipStream_t stream) {
    const int* x = (const int*)d_in[0];
    const int* w = (const int*)d_in[1];   // int8 values stored as int32
    const int* bias = (const int*)d_in[2];
    const int* shiftp = (const int*)d_in[3];
    int* out = (int*)d_out;

    const int N = in_sizes[2];      // 4096
    const int K = in_sizes[1] / N;  // 4096
    const int M = in_sizes[0] / K;  // 8192

    char* xp = (char*)d_ws;
    unsigned char* wt = (unsigned char*)d_ws + (size_t)M * K;

    int nvec = (int)(((long long)M * K) / 16);
    pack_x_kernel<<<(nvec + 255) / 256, 256, 0, stream>>>((const int32x4*)x, (int32x4*)xp, nvec);

    dim3 tgrid(N / 64, K / 64);
    transform_w_kernel<<<tgrid, 256, 0, stream>>>(w, wt, K, N);

    int nwg = (M / BM) * (N / BN);  // 512, %8==0
    gemm_i8_deep<<<nwg, 512, 0, stream>>>(xp, (const char*)wt, bias, shiftp, out, M, N, K);
}